// Round 11
// baseline (703.133 us; speedup 1.0000x reference)
//
#include <hip/hip_runtime.h>
#include <hip/hip_fp16.h>
#include <math.h>

#define DFEAT 128
#define QKD 32
#define NPART 512

typedef _Float16 half8 __attribute__((ext_vector_type(8)));
typedef float floatx4 __attribute__((ext_vector_type(4)));

static inline size_t align256(size_t x) { return (x + 255) & ~size_t(255); }

__device__ __forceinline__ __half2 u2h(unsigned u) { return *reinterpret_cast<const __half2*>(&u); }

// ---- degree + bucket histogram fused (one E-pass) ----------------------

__global__ void __launch_bounds__(1024)
hist_kernel(const int* __restrict__ eidx, unsigned* __restrict__ cnt_row,
            unsigned* __restrict__ bcount, int E, int nbuk) {
    __shared__ unsigned h[512];
    for (int i = threadIdx.x; i < 512; i += 1024) h[i] = 0;
    __syncthreads();
    int base = blockIdx.x * 8192;
    int end = base + 8192; if (end > E) end = E;
    for (int i = base + threadIdx.x; i < end; i += 1024) {
        atomicAdd(&cnt_row[eidx[i]], 1u);
        atomicAdd(&h[(unsigned)eidx[E + i] >> 8], 1u);
    }
    __syncthreads();
    for (int i = threadIdx.x; i < nbuk; i += 1024)
        if (h[i]) atomicAdd(&bcount[i], h[i]);
}

// dinv = deg^-1/2 ; dinv2 = 1/deg ; rec = deg^1/2
__global__ void dinv_kernel(const unsigned* __restrict__ cnt_row, float* __restrict__ dinv,
                            float* __restrict__ dinv2, float* __restrict__ rec, int n) {
    int i = blockIdx.x * blockDim.x + threadIdx.x;
    if (i < n) {
        unsigned c = cnt_row[i];
        if (c < 1u) c = 1u;
        float fd = (float)c;
        float sq = sqrtf(fd);
        dinv[i] = 1.0f / sq;
        dinv2[i] = 1.0f / fd;
        rec[i] = sq;
    }
}

// ---- CSC build: block-aggregated 2-pass bucket partition ---------------

__global__ void bscan_kernel(const unsigned* __restrict__ bcount, unsigned* __restrict__ bbase,
                             unsigned* __restrict__ bcur, unsigned* __restrict__ colptr,
                             int nbuk, int n, int E) {
    __shared__ unsigned s[512];
    int t = threadIdx.x;  // 512 threads
    unsigned v = (t < nbuk) ? bcount[t] : 0u;
    s[t] = v; __syncthreads();
    for (int off = 1; off < 512; off <<= 1) {
        unsigned u = (t >= off) ? s[t - off] : 0u;
        __syncthreads();
        s[t] += u;
        __syncthreads();
    }
    if (t < nbuk) { unsigned e = s[t] - v; bbase[t] = e; bcur[t] = e; }
    if (t == 0) { bbase[nbuk] = (unsigned)E; colptr[n] = (unsigned)E; }
}

__global__ void __launch_bounds__(1024)
bscatter_kernel(const int* __restrict__ eidx, unsigned* __restrict__ bcur,
                unsigned* __restrict__ pairs, int E) {
    __shared__ unsigned cnt[512];
    __shared__ unsigned cur[512];
    for (int i = threadIdx.x; i < 512; i += 1024) cnt[i] = 0;
    __syncthreads();
    int base = blockIdx.x * 8192;
    int end = base + 8192; if (end > E) end = E;
    for (int i = base + threadIdx.x; i < end; i += 1024)
        atomicAdd(&cnt[(unsigned)eidx[E + i] >> 8], 1u);
    __syncthreads();
    for (int i = threadIdx.x; i < 512; i += 1024)
        cur[i] = cnt[i] ? atomicAdd(&bcur[i], cnt[i]) : 0u;
    __syncthreads();
    for (int i = base + threadIdx.x; i < end; i += 1024) {
        int col = eidx[E + i];
        int row = eidx[i];
        unsigned pos = atomicAdd(&cur[(unsigned)col >> 8], 1u);
        pairs[pos] = ((unsigned)row << 8) | (unsigned)(col & 255);
    }
}

__global__ void __launch_bounds__(1024)
bsort_kernel(const unsigned* __restrict__ pairs, const unsigned* __restrict__ bbase,
             unsigned* __restrict__ colptr, int* __restrict__ rowlist, int n) {
    __shared__ unsigned s[256];
    __shared__ unsigned cur[256];
    int b = blockIdx.x;
    unsigned beg = bbase[b], end = bbase[b + 1];
    int t = threadIdx.x;
    if (t < 256) s[t] = 0;
    __syncthreads();
    for (unsigned i = beg + t; i < end; i += 1024)
        atomicAdd(&s[pairs[i] & 255u], 1u);
    __syncthreads();
    unsigned v = (t < 256) ? s[t] : 0u;
    for (int off = 1; off < 256; off <<= 1) {
        unsigned u = (t < 256 && t >= off) ? s[t - off] : 0u;
        __syncthreads();
        if (t < 256) s[t] += u;
        __syncthreads();
    }
    if (t < 256) {
        unsigned start = beg + (s[t] - v);
        cur[t] = start;
        int c = b * 256 + t;
        if (c < n) colptr[c] = start;
    }
    __syncthreads();
    for (unsigned i = beg + t; i < end; i += 1024) {
        unsigned pk = pairs[i];
        unsigned pos = atomicAdd(&cur[pk & 255u], 1u);
        rowlist[pos] = (int)(pk >> 8);
    }
}

// ---- y0 = fp16(dinv * h_train) -----------------------------------------

__global__ void scale_cvt_kernel(const float* __restrict__ h, const float* __restrict__ dinv,
                                 __half2* __restrict__ y, int n64) {
    int i = blockIdx.x * blockDim.x + threadIdx.x;
    if (i < n64) {
        float d = dinv[i >> 6];
        float2 v = reinterpret_cast<const float2*>(h)[i];
        y[i] = __floats2half2_rn(d * v.x, d * v.y);
    }
}

// ---- WvT fp16 -----------------------------------------------------------

__global__ void cvt_wvt_kernel(const float* __restrict__ Wv, _Float16* __restrict__ wvt) {
    int t = blockIdx.x * blockDim.x + threadIdx.x;
    if (t < DFEAT * DFEAT) {
        int j = t >> 7, d = t & 127;
        wvt[t] = (_Float16)Wv[d * DFEAT + j];
    }
}

// ---- query path ----------------------------------------------------------

__global__ void colmean_partial_kernel(const float* __restrict__ h, float* __restrict__ partialT, int n) {
    __shared__ float s[256];
    int t = threadIdx.x;
    int col = t & 127;
    int half = t >> 7;
    float acc = 0.f;
    for (int r = blockIdx.x * 2 + half; r < n; r += gridDim.x * 2)
        acc += h[(size_t)r * DFEAT + col];
    s[t] = acc; __syncthreads();
    if (t < 128) partialT[(size_t)t * NPART + blockIdx.x] = s[t] + s[t + 128];
}

__global__ void hbar_reduce_kernel(const float* __restrict__ partialT, float* __restrict__ hbar,
                                   float inv_n) {
    __shared__ float s[256];
    int c = blockIdx.x, t = threadIdx.x;
    float acc = partialT[(size_t)c * NPART + t] + partialT[(size_t)c * NPART + t + 256];
    s[t] = acc; __syncthreads();
    for (int off = 128; off > 0; off >>= 1) {
        if (t < off) s[t] += s[t + off];
        __syncthreads();
    }
    if (t == 0) hbar[c] = s[0] * inv_n;
}

__global__ void wkq_kernel(const float* __restrict__ hbar,
                           const float* __restrict__ Wq, const float* __restrict__ bq,
                           const float* __restrict__ Wk, const float* __restrict__ bk,
                           float* __restrict__ wkq_ck) {
    __shared__ float hb[DFEAT];
    __shared__ float pq[QKD][9];
    __shared__ float qg[QKD];
    int t = threadIdx.x;   // 256 threads
    if (t < DFEAT) hb[t] = hbar[t];
    __syncthreads();
    int q = t & 31, ch = t >> 5;
    float a = 0.f;
    int d0 = ch * 16;
#pragma unroll
    for (int d = 0; d < 16; ++d) a += hb[d0 + d] * Wq[(d0 + d) * QKD + q];
    pq[q][ch] = a;
    __syncthreads();
    if (t < QKD) {
        float s = bq[t];
#pragma unroll
        for (int c2 = 0; c2 < 8; ++c2) s += pq[t][c2];
        qg[t] = s;
    }
    __syncthreads();
    if (t < DFEAT) {
        float w = 0.f;
#pragma unroll
        for (int k = 0; k < QKD; ++k) w += Wk[t * QKD + k] * qg[k];
        wkq_ck[t] = w;
    }
    if (t == 0) {
        float c = 0.f;
        for (int k = 0; k < QKD; ++k) c += bk[k] * qg[k];
        wkq_ck[DFEAT] = c;
    }
}

// ---- gather core (shared) ----------------------------------------------

__device__ __forceinline__ void acc4(const uint2* __restrict__ yq, int r, int sl, float4& a) {
    uint2 v = yq[(size_t)r * 32 + sl];
    float2 f0 = __half22float2(u2h(v.x));
    float2 f1 = __half22float2(u2h(v.y));
    a.x += f0.x; a.y += f0.y; a.z += f1.x; a.w += f1.y;
}

__device__ __forceinline__ float hred(float s) {
    s += __shfl_xor(s, 1, 64);  s += __shfl_xor(s, 2, 64);  s += __shfl_xor(s, 4, 64);
    s += __shfl_xor(s, 8, 64);  s += __shfl_xor(s, 16, 64);
    return s;
}

__device__ __forceinline__ float4 gatherw(const uint2* __restrict__ y,
                                          const int* __restrict__ rowlist,
                                          unsigned beg, unsigned deg, unsigned mxd, int sl) {
    float4 a = make_float4(0.f, 0.f, 0.f, 0.f);
    unsigned i = 0;
    for (; i < (mxd & ~7u); i += 8) {
        unsigned rem = deg > i ? deg - i : 0;
        if (rem >= 8) {
            int4 q0 = *reinterpret_cast<const int4*>(&rowlist[beg + i]);
            int4 q1 = *reinterpret_cast<const int4*>(&rowlist[beg + i + 4]);
            uint2 v0 = y[(size_t)q0.x * 32 + sl];
            uint2 v1 = y[(size_t)q0.y * 32 + sl];
            uint2 v2 = y[(size_t)q0.z * 32 + sl];
            uint2 v3 = y[(size_t)q0.w * 32 + sl];
            uint2 v4 = y[(size_t)q1.x * 32 + sl];
            uint2 v5 = y[(size_t)q1.y * 32 + sl];
            uint2 v6 = y[(size_t)q1.z * 32 + sl];
            uint2 v7 = y[(size_t)q1.w * 32 + sl];
            __half2 sx = __hadd2(__hadd2(__hadd2(u2h(v0.x), u2h(v1.x)), __hadd2(u2h(v2.x), u2h(v3.x))),
                                 __hadd2(__hadd2(u2h(v4.x), u2h(v5.x)), __hadd2(u2h(v6.x), u2h(v7.x))));
            __half2 sy = __hadd2(__hadd2(__hadd2(u2h(v0.y), u2h(v1.y)), __hadd2(u2h(v2.y), u2h(v3.y))),
                                 __hadd2(__hadd2(u2h(v4.y), u2h(v5.y)), __hadd2(u2h(v6.y), u2h(v7.y))));
            float2 fx = __half22float2(sx), fy = __half22float2(sy);
            a.x += fx.x; a.y += fx.y; a.z += fy.x; a.w += fy.y;
        } else if (rem >= 4) {
            int4 q = *reinterpret_cast<const int4*>(&rowlist[beg + i]);
            uint2 v0 = y[(size_t)q.x * 32 + sl];
            uint2 v1 = y[(size_t)q.y * 32 + sl];
            uint2 v2 = y[(size_t)q.z * 32 + sl];
            uint2 v3 = y[(size_t)q.w * 32 + sl];
            __half2 sx = __hadd2(__hadd2(u2h(v0.x), u2h(v1.x)), __hadd2(u2h(v2.x), u2h(v3.x)));
            __half2 sy = __hadd2(__hadd2(u2h(v0.y), u2h(v1.y)), __hadd2(u2h(v2.y), u2h(v3.y)));
            float2 fx = __half22float2(sx), fy = __half22float2(sy);
            a.x += fx.x; a.y += fx.y; a.z += fy.x; a.w += fy.y;
            for (unsigned k = 4; k < rem; ++k) acc4(y, rowlist[beg + i + k], sl, a);
        } else if (rem) {
            for (unsigned k = 0; k < rem; ++k) acc4(y, rowlist[beg + i + k], sl, a);
        }
    }
    {
        unsigned rem = deg > i ? deg - i : 0;
        if (rem >= 4) {
            int4 q = *reinterpret_cast<const int4*>(&rowlist[beg + i]);
            uint2 v0 = y[(size_t)q.x * 32 + sl];
            uint2 v1 = y[(size_t)q.y * 32 + sl];
            uint2 v2 = y[(size_t)q.z * 32 + sl];
            uint2 v3 = y[(size_t)q.w * 32 + sl];
            __half2 sx = __hadd2(__hadd2(u2h(v0.x), u2h(v1.x)), __hadd2(u2h(v2.x), u2h(v3.x)));
            __half2 sy = __hadd2(__hadd2(u2h(v0.y), u2h(v1.y)), __hadd2(u2h(v2.y), u2h(v3.y)));
            float2 fx = __half22float2(sx), fy = __half22float2(sy);
            a.x += fx.x; a.y += fx.y; a.z += fy.x; a.w += fy.y;
            for (unsigned k = 4; k < rem; ++k) acc4(y, rowlist[beg + i + k], sl, a);
        } else if (rem) {
            for (unsigned k = 0; k < rem; ++k) acc4(y, rowlist[beg + i + k], sl, a);
        }
    }
    return a;
}

__device__ __forceinline__ uint2 pack4(float a, float b, float c, float d) {
    uint2 r;
    __half2 h0 = __floats2half2_rn(a, b), h1 = __floats2half2_rn(c, d);
    r.x = *reinterpret_cast<unsigned*>(&h0);
    r.y = *reinterpret_cast<unsigned*>(&h1);
    return r;
}

// ================= STACK PATH (deferred softmax; no U RMW) ==============

__global__ void __launch_bounds__(256, 8)
prop0_st_kernel(const uint2* __restrict__ y0,
                const int* __restrict__ rowlist, const unsigned* __restrict__ colptr,
                const float* __restrict__ dinv, const float* __restrict__ rec,
                const float* __restrict__ wkq_ck,
                uint2* __restrict__ afeat_out, uint2* __restrict__ y1_out,
                float* __restrict__ score01, int n) {
    int wid = threadIdx.x >> 6, lane = threadIdx.x & 63;
    int sub = lane >> 5, sl = lane & 31;
    int c = blockIdx.x * 8 + wid * 2 + sub;
    if (c >= n) c = n - 1;
    unsigned beg = colptr[c], end = colptr[c + 1];
    unsigned deg = end - beg;
    unsigned dego = __shfl_xor(deg, 32, 64);
    unsigned mxd = deg > dego ? deg : dego;
    float4 a = gatherw(y0, rowlist, beg, deg, mxd, sl);

    float dc = dinv[c], rc = rec[c];
    size_t off = (size_t)c * 32 + sl;
    uint2 bvv = y0[off];
    float2 b0 = __half22float2(u2h(bvv.x));
    float2 b1 = __half22float2(u2h(bvv.y));
    float x0 = rc * b0.x, x1 = rc * b0.y, x2 = rc * b1.x, x3 = rc * b1.y;
    float p0 = dc * a.x, p1 = dc * a.y, p2 = dc * a.z, p3 = dc * a.w;
    float ad0 = x0 + p0, ad1 = x1 + p1, ad2 = x2 + p2, ad3 = x3 + p3;
    float sb0 = x0 - p0, sb1 = x1 - p1, sb2 = x2 - p2, sb3 = x3 - p3;
    afeat_out[off] = pack4(ad0, ad1, ad2, ad3);              // x-space
    y1_out[off] = pack4(dc * sb0, dc * sb1, dc * sb2, dc * sb3);  // y-space

    const float scale = 0.08838834764831845f;  // 1/sqrt(128)
    float ck = wkq_ck[DFEAT];
    float4 wv = *reinterpret_cast<const float4*>(&wkq_ck[sl * 4]);
    float s0 = (hred(ad0 * wv.x + ad1 * wv.y + ad2 * wv.z + ad3 * wv.w) + ck) * scale;
    float s1 = (hred(sb0 * wv.x + sb1 * wv.y + sb2 * wv.z + sb3 * wv.w) + ck) * scale;
    if (sl == 0) { score01[c] = s0; score01[n + c] = s1; }
}

__global__ void __launch_bounds__(256, 8)
prop_st_kernel(const uint2* __restrict__ y, const int* __restrict__ rowlist,
               const unsigned* __restrict__ colptr,
               const float* __restrict__ dinv2, const float* __restrict__ rec,
               const float* __restrict__ wkq_ck,
               uint2* __restrict__ yout, float* __restrict__ score_out, int n) {
    int wid = threadIdx.x >> 6, lane = threadIdx.x & 63;
    int sub = lane >> 5, sl = lane & 31;
    int c = blockIdx.x * 8 + wid * 2 + sub;
    if (c >= n) c = n - 1;
    unsigned beg = colptr[c], end = colptr[c + 1];
    unsigned deg = end - beg;
    unsigned dego = __shfl_xor(deg, 32, 64);
    unsigned mxd = deg > dego ? deg : dego;
    float4 a = gatherw(y, rowlist, beg, deg, mxd, sl);

    float d2 = dinv2[c], rc = rec[c];
    size_t off = (size_t)c * 32 + sl;
    uint2 bvv = y[off];
    float2 b0 = __half22float2(u2h(bvv.x));
    float2 b1 = __half22float2(u2h(bvv.y));
    float y0 = b0.x - d2 * a.x, y1 = b0.y - d2 * a.y;
    float y2 = b1.x - d2 * a.z, y3 = b1.y - d2 * a.w;
    yout[off] = pack4(y0, y1, y2, y3);
    float x0 = rc * y0, x1 = rc * y1, x2 = rc * y2, x3 = rc * y3;

    const float scale = 0.08838834764831845f;
    float ck = wkq_ck[DFEAT];
    float4 wv = *reinterpret_cast<const float4*>(&wkq_ck[sl * 4]);
    float s = (hred(x0 * wv.x + x1 * wv.y + x2 * wv.z + x3 * wv.w) + ck) * scale;
    if (sl == 0) score_out[c] = s;
}

// final: softmax(scores) -> fp16 blend of 8 stack rows -> MFMA GEMM + bv
__global__ void __launch_bounds__(256, 4)
final_stack_kernel(const _Float16* __restrict__ stack, size_t sstride,
                   const float* __restrict__ score, const float* __restrict__ rec,
                   const unsigned* __restrict__ wvtU, const float* __restrict__ bv,
                   float* __restrict__ out, int n) {
    __shared__ unsigned wT[8192];
    for (int i = threadIdx.x; i < 8192; i += 256) {
        int col = i >> 6, inner = i & 63;
        wT[col * 64 + (inner ^ ((col & 7) << 2))] = wvtU[i];
    }
    __syncthreads();
    int wave = threadIdx.x >> 6, lane = threadIdx.x & 63;
    int row0 = blockIdx.x * 64 + wave * 16;
    int l15 = lane & 15, grp = lane >> 4;
    int kgrp = grp * 8;
    int arow = row0 + l15; if (arow >= n) arow = n - 1;
    float sc[8];
#pragma unroll
    for (int t = 0; t < 8; ++t) sc[t] = score[(size_t)t * n + arow];
    float mx = sc[0];
#pragma unroll
    for (int t = 1; t < 8; ++t) mx = fmaxf(mx, sc[t]);
    float se = 0.f;
#pragma unroll
    for (int t = 0; t < 8; ++t) { sc[t] = expf(sc[t] - mx); se += sc[t]; }
    float inv = 1.0f / se;
    float rc = rec[arow];
    __half2 wh[8];
#pragma unroll
    for (int t = 0; t < 8; ++t) wh[t] = __float2half2_rn(sc[t] * inv * (t ? rc : 1.0f));
    const _Float16* aptr = stack + (size_t)arow * DFEAT + kgrp;
    half8 af[4];
#pragma unroll
    for (int kt = 0; kt < 4; ++kt) {
        __half2 a0 = __float2half2_rn(0.f), a1 = a0, a2 = a0, a3 = a0;
#pragma unroll
        for (int t = 0; t < 8; ++t) {
            uint4 v = *reinterpret_cast<const uint4*>(aptr + (size_t)t * sstride + kt * 32);
            a0 = __hfma2(wh[t], u2h(v.x), a0);
            a1 = __hfma2(wh[t], u2h(v.y), a1);
            a2 = __hfma2(wh[t], u2h(v.z), a2);
            a3 = __hfma2(wh[t], u2h(v.w), a3);
        }
        uint4 au;
        au.x = *reinterpret_cast<unsigned*>(&a0);
        au.y = *reinterpret_cast<unsigned*>(&a1);
        au.z = *reinterpret_cast<unsigned*>(&a2);
        au.w = *reinterpret_cast<unsigned*>(&a3);
        af[kt] = *reinterpret_cast<half8*>(&au);
    }
    const _Float16* wTh = (const _Float16*)wT;
    floatx4 acc[8];
#pragma unroll
    for (int ct = 0; ct < 8; ++ct) acc[ct] = (floatx4){0.f, 0.f, 0.f, 0.f};
#pragma unroll
    for (int kt = 0; kt < 4; ++kt) {
        int kbase = kt * 32 + kgrp;
#pragma unroll
        for (int ct = 0; ct < 8; ++ct) {
            int col = ct * 16 + l15;
            half8 bf = *(const half8*)&wTh[col * 128 + (kbase ^ ((col & 7) << 3))];
            acc[ct] = __builtin_amdgcn_mfma_f32_16x16x32_f16(af[kt], bf, acc[ct], 0, 0, 0);
        }
    }
    int m0 = row0 + grp * 4;
#pragma unroll
    for (int ct = 0; ct < 8; ++ct) {
        int col = ct * 16 + l15;
        float bvc = bv[col];
#pragma unroll
        for (int r = 0; r < 4; ++r) {
            int gr = m0 + r;
            if (gr < n) out[(size_t)gr * DFEAT + col] = acc[ct][r] + bvc;
        }
    }
}

// ================= FALLBACK PATH (round-10: online softmax) =============

__global__ void __launch_bounds__(256, 8)
prop0_kernel(const uint2* __restrict__ y0,
             const int* __restrict__ rowlist, const unsigned* __restrict__ colptr,
             const float* __restrict__ dinv, const float* __restrict__ rec,
             const float* __restrict__ wkq_ck,
             uint2* __restrict__ yout, uint2* __restrict__ U,
             float* __restrict__ m_run, float* __restrict__ den_run, int n) {
    int wid = threadIdx.x >> 6, lane = threadIdx.x & 63;
    int sub = lane >> 5, sl = lane & 31;
    int c = blockIdx.x * 8 + wid * 2 + sub;
    if (c >= n) c = n - 1;
    unsigned beg = colptr[c], end = colptr[c + 1];
    unsigned deg = end - beg;
    unsigned dego = __shfl_xor(deg, 32, 64);
    unsigned mxd = deg > dego ? deg : dego;
    float4 a = gatherw(y0, rowlist, beg, deg, mxd, sl);

    float dc = dinv[c], rc = rec[c];
    size_t off = (size_t)c * 32 + sl;
    uint2 bvv = y0[off];
    float2 b0 = __half22float2(u2h(bvv.x));
    float2 b1 = __half22float2(u2h(bvv.y));
    float x0 = rc * b0.x, x1 = rc * b0.y, x2 = rc * b1.x, x3 = rc * b1.y;
    float p0 = dc * a.x, p1 = dc * a.y, p2 = dc * a.z, p3 = dc * a.w;
    float ad0 = x0 + p0, ad1 = x1 + p1, ad2 = x2 + p2, ad3 = x3 + p3;
    float sb0 = x0 - p0, sb1 = x1 - p1, sb2 = x2 - p2, sb3 = x3 - p3;
    yout[off] = pack4(dc * sb0, dc * sb1, dc * sb2, dc * sb3);

    const float scale = 0.08838834764831845f;
    float ck = wkq_ck[DFEAT];
    float4 wv = *reinterpret_cast<const float4*>(&wkq_ck[sl * 4]);
    float s0 = (hred(ad0 * wv.x + ad1 * wv.y + ad2 * wv.z + ad3 * wv.w) + ck) * scale;
    float s1 = (hred(sb0 * wv.x + sb1 * wv.y + sb2 * wv.z + sb3 * wv.w) + ck) * scale;
    float m = fmaxf(s0, s1);
    float e0 = expf(s0 - m), e1 = expf(s1 - m);
    U[off] = pack4(e0 * ad0 + e1 * sb0, e0 * ad1 + e1 * sb1,
                   e0 * ad2 + e1 * sb2, e0 * ad3 + e1 * sb3);
    if (sl == 0) { m_run[c] = m; den_run[c] = e0 + e1; }
}

__global__ void __launch_bounds__(256, 8)
prop_fused_kernel(const uint2* __restrict__ y, const int* __restrict__ rowlist,
                  const unsigned* __restrict__ colptr,
                  const float* __restrict__ dinv2, const float* __restrict__ rec,
                  const float* __restrict__ wkq_ck,
                  uint2* __restrict__ yout, uint2* __restrict__ U,
                  float* __restrict__ m_run, float* __restrict__ den_run, int n) {
    int wid = threadIdx.x >> 6, lane = threadIdx.x & 63;
    int sub = lane >> 5, sl = lane & 31;
    int c = blockIdx.x * 8 + wid * 2 + sub;
    if (c >= n) c = n - 1;
    unsigned beg = colptr[c], end = colptr[c + 1];
    unsigned deg = end - beg;
    unsigned dego = __shfl_xor(deg, 32, 64);
    unsigned mxd = deg > dego ? deg : dego;
    float4 a = gatherw(y, rowlist, beg, deg, mxd, sl);

    float d2 = dinv2[c], rc = rec[c];
    size_t off = (size_t)c * 32 + sl;
    uint2 bvv = y[off];
    float2 b0 = __half22float2(u2h(bvv.x));
    float2 b1 = __half22float2(u2h(bvv.y));
    float y0 = b0.x - d2 * a.x, y1 = b0.y - d2 * a.y;
    float y2 = b1.x - d2 * a.z, y3 = b1.y - d2 * a.w;
    yout[off] = pack4(y0, y1, y2, y3);
    float x0 = rc * y0, x1 = rc * y1, x2 = rc * y2, x3 = rc * y3;

    const float scale = 0.08838834764831845f;
    float ck = wkq_ck[DFEAT];
    float4 wv = *reinterpret_cast<const float4*>(&wkq_ck[sl * 4]);
    float s = (hred(x0 * wv.x + x1 * wv.y + x2 * wv.z + x3 * wv.w) + ck) * scale;
    float m = m_run[c], den = den_run[c];
    float m2 = fmaxf(m, s);
    float alpha = expf(m - m2), beta = expf(s - m2);
    uint2 uv = U[off];
    float2 u0 = __half22float2(u2h(uv.x));
    float2 u1 = __half22float2(u2h(uv.y));
    U[off] = pack4(u0.x * alpha + beta * x0, u0.y * alpha + beta * x1,
                   u1.x * alpha + beta * x2, u1.y * alpha + beta * x3);
    if (sl == 0) { m_run[c] = m2; den_run[c] = den * alpha + beta; }
}

__global__ void __launch_bounds__(256, 4)
final_mfma_kernel(const _Float16* __restrict__ Uh, const float* __restrict__ den,
                  const unsigned* __restrict__ wvtU, const float* __restrict__ bv,
                  float* __restrict__ out, int n) {
    __shared__ unsigned wT[8192];
    for (int i = threadIdx.x; i < 8192; i += 256) {
        int col = i >> 6, inner = i & 63;
        wT[col * 64 + (inner ^ ((col & 7) << 2))] = wvtU[i];
    }
    __syncthreads();
    int wave = threadIdx.x >> 6, lane = threadIdx.x & 63;
    int row0 = blockIdx.x * 64 + wave * 16;
    int l15 = lane & 15, grp = lane >> 4;
    int kgrp = grp * 8;
    int arow = row0 + l15; if (arow >= n) arow = n - 1;
    const _Float16* aptr = Uh + (size_t)arow * DFEAT + kgrp;
    half8 af[4];
    af[0] = *(const half8*)(aptr);
    af[1] = *(const half8*)(aptr + 32);
    af[2] = *(const half8*)(aptr + 64);
    af[3] = *(const half8*)(aptr + 96);
    const _Float16* wTh = (const _Float16*)wT;
    floatx4 acc[8];
#pragma unroll
    for (int ct = 0; ct < 8; ++ct) acc[ct] = (floatx4){0.f, 0.f, 0.f, 0.f};
#pragma unroll
    for (int kt = 0; kt < 4; ++kt) {
        int kbase = kt * 32 + kgrp;
#pragma unroll
        for (int ct = 0; ct < 8; ++ct) {
            int col = ct * 16 + l15;
            half8 bf = *(const half8*)&wTh[col * 128 + (kbase ^ ((col & 7) << 3))];
            acc[ct] = __builtin_amdgcn_mfma_f32_16x16x32_f16(af[kt], bf, acc[ct], 0, 0, 0);
        }
    }
    int m0 = row0 + grp * 4;
    float invd[4];
#pragma unroll
    for (int r = 0; r < 4; ++r) {
        int gr = m0 + r;
        invd[r] = 1.0f / den[gr < n ? gr : (n - 1)];
    }
#pragma unroll
    for (int ct = 0; ct < 8; ++ct) {
        int col = ct * 16 + l15;
        float bvc = bv[col];
#pragma unroll
        for (int r = 0; r < 4; ++r) {
            int gr = m0 + r;
            if (gr < n) out[(size_t)gr * DFEAT + col] = acc[ct][r] * invd[r] + bvc;
        }
    }
}

// ------------------------------------------------------------------------

extern "C" void kernel_launch(void* const* d_in, const int* in_sizes, int n_in,
                              void* d_out, int out_size, void* d_ws, size_t ws_size,
                              hipStream_t stream) {
    const float* h_train = (const float*)d_in[0];
    const float* h_ori   = (const float*)d_in[1];
    const int*   eidx    = (const int*)d_in[2];
    const float* Wq = (const float*)d_in[3];
    const float* bq = (const float*)d_in[4];
    const float* Wk = (const float*)d_in[5];
    const float* bk = (const float*)d_in[6];
    const float* Wv = (const float*)d_in[7];
    const float* bv = (const float*)d_in[8];
    float* out = (float*)d_out;

    const int n = in_sizes[0] / DFEAT;   // 100000
    const int E = in_sizes[2] / 2;       // 1600000
    const int NBUK = (n + 255) >> 8;     // 391
    const int EB = (E + 8191) / 8192;    // 196
    size_t FB = align256((size_t)n * 256);   // bytes per fp16 feature buffer

    if (NBUK > 512) return;

    // small/shared carve
    char* p = (char*)d_ws;
    auto alloc = [&](size_t bytes) { char* r = p; p += align256(bytes); return r; };
    int*      rowlist  = (int*)     alloc((size_t)(E + 16) * 4);
    unsigned* pairs    = (unsigned*)alloc((size_t)E * 4);
    float*    dinv     = (float*)   alloc((size_t)n * 4);
    float*    dinv2    = (float*)   alloc((size_t)n * 4);
    float*    rec      = (float*)   alloc((size_t)n * 4);
    unsigned* cnt_row  = (unsigned*)alloc((size_t)n * 4);
    unsigned* colptr   = (unsigned*)alloc((size_t)(n + 1) * 4);
    unsigned* bcount   = (unsigned*)alloc((size_t)NBUK * 4);
    unsigned* bbase    = (unsigned*)alloc((size_t)(NBUK + 1) * 4);
    unsigned* bcur     = (unsigned*)alloc((size_t)NBUK * 4);
    float*    m_run    = (float*)   alloc((size_t)n * 4);
    float*    den_run  = (float*)   alloc((size_t)n * 4);
    float*    score    = (float*)   alloc((size_t)8 * n * 4);
    float*    partialT = (float*)   alloc((size_t)NPART * DFEAT * 4);
    float*    hbar     = (float*)   alloc(DFEAT * 4);
    float*    wkq_ck   = (float*)   alloc((DFEAT + 1) * 4);
    _Float16* wvt      = (_Float16*)alloc((size_t)DFEAT * DFEAT * 2);

    size_t used = (size_t)(p - (char*)d_ws);
    bool use_stack = (used + 9 * FB) <= ws_size;   // y0 + 8 stack slots (~250 MB)
    uint2* y0 = nullptr; char* stack = nullptr;
    uint2 *yA = nullptr, *yB = nullptr, *U16 = nullptr;
    if (use_stack) {
        y0    = (uint2*)alloc(FB);
        stack = (char*)alloc(8 * FB);
    } else {
        if (used + 3 * FB > ws_size) return;  // fail loud
        yA  = (uint2*)alloc(FB);
        yB  = (uint2*)alloc(FB);
        U16 = (uint2*)alloc(FB);
    }

    hipMemsetAsync(cnt_row, 0, (size_t)n * 4, stream);
    hipMemsetAsync(bcount, 0, (size_t)NBUK * 4, stream);

    hist_kernel<<<EB, 1024, 0, stream>>>(eidx, cnt_row, bcount, E, NBUK);
    bscan_kernel<<<1, 512, 0, stream>>>(bcount, bbase, bcur, colptr, NBUK, n, E);
    bscatter_kernel<<<EB, 1024, 0, stream>>>(eidx, bcur, pairs, E);
    dinv_kernel<<<(n + 255) / 256, 256, 0, stream>>>(cnt_row, dinv, dinv2, rec, n);
    bsort_kernel<<<NBUK, 1024, 0, stream>>>(pairs, bbase, colptr, rowlist, n);

    cvt_wvt_kernel<<<64, 256, 0, stream>>>(Wv, wvt);
    colmean_partial_kernel<<<NPART, 256, 0, stream>>>(h_ori, partialT, n);
    hbar_reduce_kernel<<<DFEAT, 256, 0, stream>>>(partialT, hbar, 1.0f / (float)n);
    wkq_kernel<<<1, 256, 0, stream>>>(hbar, Wq, bq, Wk, bk, wkq_ck);

    int pgrid = (n + 7) / 8;
    if (use_stack) {
        auto slotu = [&](int t) { return (uint2*)(stack + (size_t)t * FB); };
        scale_cvt_kernel<<<(n * 64 + 255) / 256, 256, 0, stream>>>(h_train, dinv, (__half2*)y0, n * 64);
        // hop0: a_feat -> slot0, y1 -> slot1, scores s0,s1
        prop0_st_kernel<<<pgrid, 256, 0, stream>>>(y0, rowlist, colptr, dinv, rec, wkq_ck,
                                                   slotu(0), slotu(1), score, n);
        for (int t = 2; t <= 7; ++t)
            prop_st_kernel<<<pgrid, 256, 0, stream>>>(slotu(t - 1), rowlist, colptr, dinv2, rec,
                                                      wkq_ck, slotu(t), score + (size_t)t * n, n);
        final_stack_kernel<<<(n + 63) / 64, 256, 0, stream>>>((const _Float16*)stack, FB / 2,
                                                              score, rec, (const unsigned*)wvt,
                                                              bv, out, n);
    } else {
        scale_cvt_kernel<<<(n * 64 + 255) / 256, 256, 0, stream>>>(h_train, dinv, (__half2*)yA, n * 64);
        prop0_kernel<<<pgrid, 256, 0, stream>>>(yA, rowlist, colptr, dinv, rec, wkq_ck,
                                                yB, U16, m_run, den_run, n);
        uint2* xin = yB; uint2* xout = yA;
        for (int t = 2; t <= 7; ++t) {
            prop_fused_kernel<<<pgrid, 256, 0, stream>>>(xin, rowlist, colptr, dinv2, rec, wkq_ck,
                                                         xout, U16, m_run, den_run, n);
            uint2* tmp = xin; xin = xout; xout = tmp;
        }
        final_mfma_kernel<<<(n + 63) / 64, 256, 0, stream>>>((const _Float16*)U16, den_run,
                                                             (const unsigned*)wvt, bv, out, n);
    }
}

// Round 12
// 677.229 us; speedup vs baseline: 1.0382x; 1.0382x over previous
//
#include <hip/hip_runtime.h>
#include <hip/hip_fp16.h>
#include <math.h>

#define DFEAT 128
#define QKD 32
#define NPART 512

typedef _Float16 half8 __attribute__((ext_vector_type(8)));
typedef float floatx4 __attribute__((ext_vector_type(4)));

static inline size_t align256(size_t x) { return (x + 255) & ~size_t(255); }

__device__ __forceinline__ __half2 u2h(unsigned u) { return *reinterpret_cast<const __half2*>(&u); }

// ---- degree + bucket histogram fused (one E-pass) ----------------------

__global__ void __launch_bounds__(1024)
hist_kernel(const int* __restrict__ eidx, unsigned* __restrict__ cnt_row,
            unsigned* __restrict__ bcount, int E, int nbuk) {
    __shared__ unsigned h[512];
    for (int i = threadIdx.x; i < 512; i += 1024) h[i] = 0;
    __syncthreads();
    int base = blockIdx.x * 8192;
    int end = base + 8192; if (end > E) end = E;
    for (int i = base + threadIdx.x; i < end; i += 1024) {
        atomicAdd(&cnt_row[eidx[i]], 1u);
        atomicAdd(&h[(unsigned)eidx[E + i] >> 8], 1u);
    }
    __syncthreads();
    for (int i = threadIdx.x; i < nbuk; i += 1024)
        if (h[i]) atomicAdd(&bcount[i], h[i]);
}

// dinv = deg^-1/2 ; dinv2 = 1/deg ; rec = deg^1/2
__global__ void dinv_kernel(const unsigned* __restrict__ cnt_row, float* __restrict__ dinv,
                            float* __restrict__ dinv2, float* __restrict__ rec, int n) {
    int i = blockIdx.x * blockDim.x + threadIdx.x;
    if (i < n) {
        unsigned c = cnt_row[i];
        if (c < 1u) c = 1u;
        float fd = (float)c;
        float sq = sqrtf(fd);
        dinv[i] = 1.0f / sq;
        dinv2[i] = 1.0f / fd;
        rec[i] = sq;
    }
}

// ---- CSC build: block-aggregated 2-pass bucket partition ---------------

__global__ void bscan_kernel(const unsigned* __restrict__ bcount, unsigned* __restrict__ bbase,
                             unsigned* __restrict__ bcur, unsigned* __restrict__ colptr,
                             int nbuk, int n, int E) {
    __shared__ unsigned s[512];
    int t = threadIdx.x;  // 512 threads
    unsigned v = (t < nbuk) ? bcount[t] : 0u;
    s[t] = v; __syncthreads();
    for (int off = 1; off < 512; off <<= 1) {
        unsigned u = (t >= off) ? s[t - off] : 0u;
        __syncthreads();
        s[t] += u;
        __syncthreads();
    }
    if (t < nbuk) { unsigned e = s[t] - v; bbase[t] = e; bcur[t] = e; }
    if (t == 0) { bbase[nbuk] = (unsigned)E; colptr[n] = (unsigned)E; }
}

__global__ void __launch_bounds__(1024)
bscatter_kernel(const int* __restrict__ eidx, unsigned* __restrict__ bcur,
                unsigned* __restrict__ pairs, int E) {
    __shared__ unsigned cnt[512];
    __shared__ unsigned cur[512];
    for (int i = threadIdx.x; i < 512; i += 1024) cnt[i] = 0;
    __syncthreads();
    int base = blockIdx.x * 8192;
    int end = base + 8192; if (end > E) end = E;
    for (int i = base + threadIdx.x; i < end; i += 1024)
        atomicAdd(&cnt[(unsigned)eidx[E + i] >> 8], 1u);
    __syncthreads();
    for (int i = threadIdx.x; i < 512; i += 1024)
        cur[i] = cnt[i] ? atomicAdd(&bcur[i], cnt[i]) : 0u;
    __syncthreads();
    for (int i = base + threadIdx.x; i < end; i += 1024) {
        int col = eidx[E + i];
        int row = eidx[i];
        unsigned pos = atomicAdd(&cur[(unsigned)col >> 8], 1u);
        pairs[pos] = ((unsigned)row << 8) | (unsigned)(col & 255);
    }
}

__global__ void __launch_bounds__(1024)
bsort_kernel(const unsigned* __restrict__ pairs, const unsigned* __restrict__ bbase,
             unsigned* __restrict__ colptr, int* __restrict__ rowlist, int n) {
    __shared__ unsigned s[256];
    __shared__ unsigned cur[256];
    int b = blockIdx.x;
    unsigned beg = bbase[b], end = bbase[b + 1];
    int t = threadIdx.x;
    if (t < 256) s[t] = 0;
    __syncthreads();
    for (unsigned i = beg + t; i < end; i += 1024)
        atomicAdd(&s[pairs[i] & 255u], 1u);
    __syncthreads();
    unsigned v = (t < 256) ? s[t] : 0u;
    for (int off = 1; off < 256; off <<= 1) {
        unsigned u = (t < 256 && t >= off) ? s[t - off] : 0u;
        __syncthreads();
        if (t < 256) s[t] += u;
        __syncthreads();
    }
    if (t < 256) {
        unsigned start = beg + (s[t] - v);
        cur[t] = start;
        int c = b * 256 + t;
        if (c < n) colptr[c] = start;
    }
    __syncthreads();
    for (unsigned i = beg + t; i < end; i += 1024) {
        unsigned pk = pairs[i];
        unsigned pos = atomicAdd(&cur[pk & 255u], 1u);
        rowlist[pos] = (int)(pk >> 8);
    }
}

// ---- y0 = fp16(dinv * h_train) -----------------------------------------

__global__ void scale_cvt_kernel(const float* __restrict__ h, const float* __restrict__ dinv,
                                 __half2* __restrict__ y, int n64) {
    int i = blockIdx.x * blockDim.x + threadIdx.x;
    if (i < n64) {
        float d = dinv[i >> 6];
        float2 v = reinterpret_cast<const float2*>(h)[i];
        y[i] = __floats2half2_rn(d * v.x, d * v.y);
    }
}

// ---- WvT fp16 -----------------------------------------------------------

__global__ void cvt_wvt_kernel(const float* __restrict__ Wv, _Float16* __restrict__ wvt) {
    int t = blockIdx.x * blockDim.x + threadIdx.x;
    if (t < DFEAT * DFEAT) {
        int j = t >> 7, d = t & 127;
        wvt[t] = (_Float16)Wv[d * DFEAT + j];
    }
}

// ---- query path ----------------------------------------------------------

__global__ void colmean_partial_kernel(const float* __restrict__ h, float* __restrict__ partialT, int n) {
    __shared__ float s[256];
    int t = threadIdx.x;
    int col = t & 127;
    int half = t >> 7;
    float acc = 0.f;
    for (int r = blockIdx.x * 2 + half; r < n; r += gridDim.x * 2)
        acc += h[(size_t)r * DFEAT + col];
    s[t] = acc; __syncthreads();
    if (t < 128) partialT[(size_t)t * NPART + blockIdx.x] = s[t] + s[t + 128];
}

__global__ void hbar_reduce_kernel(const float* __restrict__ partialT, float* __restrict__ hbar,
                                   float inv_n) {
    __shared__ float s[256];
    int c = blockIdx.x, t = threadIdx.x;
    float acc = partialT[(size_t)c * NPART + t] + partialT[(size_t)c * NPART + t + 256];
    s[t] = acc; __syncthreads();
    for (int off = 128; off > 0; off >>= 1) {
        if (t < off) s[t] += s[t + off];
        __syncthreads();
    }
    if (t == 0) hbar[c] = s[0] * inv_n;
}

__global__ void wkq_kernel(const float* __restrict__ hbar,
                           const float* __restrict__ Wq, const float* __restrict__ bq,
                           const float* __restrict__ Wk, const float* __restrict__ bk,
                           float* __restrict__ wkq_ck) {
    __shared__ float hb[DFEAT];
    __shared__ float pq[QKD][9];
    __shared__ float qg[QKD];
    int t = threadIdx.x;   // 256 threads
    if (t < DFEAT) hb[t] = hbar[t];
    __syncthreads();
    int q = t & 31, ch = t >> 5;
    float a = 0.f;
    int d0 = ch * 16;
#pragma unroll
    for (int d = 0; d < 16; ++d) a += hb[d0 + d] * Wq[(d0 + d) * QKD + q];
    pq[q][ch] = a;
    __syncthreads();
    if (t < QKD) {
        float s = bq[t];
#pragma unroll
        for (int c2 = 0; c2 < 8; ++c2) s += pq[t][c2];
        qg[t] = s;
    }
    __syncthreads();
    if (t < DFEAT) {
        float w = 0.f;
#pragma unroll
        for (int k = 0; k < QKD; ++k) w += Wk[t * QKD + k] * qg[k];
        wkq_ck[t] = w;
    }
    if (t == 0) {
        float c = 0.f;
        for (int k = 0; k < QKD; ++k) c += bk[k] * qg[k];
        wkq_ck[DFEAT] = c;
    }
}

// ---- gather core --------------------------------------------------------

__device__ __forceinline__ void acc4(const uint2* __restrict__ yq, int r, int sl, float4& a) {
    uint2 v = yq[(size_t)r * 32 + sl];
    float2 f0 = __half22float2(u2h(v.x));
    float2 f1 = __half22float2(u2h(v.y));
    a.x += f0.x; a.y += f0.y; a.z += f1.x; a.w += f1.y;
}

__device__ __forceinline__ float hred(float s) {
    s += __shfl_xor(s, 1, 64);  s += __shfl_xor(s, 2, 64);  s += __shfl_xor(s, 4, 64);
    s += __shfl_xor(s, 8, 64);  s += __shfl_xor(s, 16, 64);
    return s;
}

__device__ __forceinline__ float4 gatherw(const uint2* __restrict__ y,
                                          const int* __restrict__ rowlist,
                                          unsigned beg, unsigned deg, unsigned mxd, int sl) {
    float4 a = make_float4(0.f, 0.f, 0.f, 0.f);
    unsigned i = 0;
    for (; i < (mxd & ~7u); i += 8) {
        unsigned rem = deg > i ? deg - i : 0;
        if (rem >= 8) {
            int4 q0 = *reinterpret_cast<const int4*>(&rowlist[beg + i]);
            int4 q1 = *reinterpret_cast<const int4*>(&rowlist[beg + i + 4]);
            uint2 v0 = y[(size_t)q0.x * 32 + sl];
            uint2 v1 = y[(size_t)q0.y * 32 + sl];
            uint2 v2 = y[(size_t)q0.z * 32 + sl];
            uint2 v3 = y[(size_t)q0.w * 32 + sl];
            uint2 v4 = y[(size_t)q1.x * 32 + sl];
            uint2 v5 = y[(size_t)q1.y * 32 + sl];
            uint2 v6 = y[(size_t)q1.z * 32 + sl];
            uint2 v7 = y[(size_t)q1.w * 32 + sl];
            __half2 sx = __hadd2(__hadd2(__hadd2(u2h(v0.x), u2h(v1.x)), __hadd2(u2h(v2.x), u2h(v3.x))),
                                 __hadd2(__hadd2(u2h(v4.x), u2h(v5.x)), __hadd2(u2h(v6.x), u2h(v7.x))));
            __half2 sy = __hadd2(__hadd2(__hadd2(u2h(v0.y), u2h(v1.y)), __hadd2(u2h(v2.y), u2h(v3.y))),
                                 __hadd2(__hadd2(u2h(v4.y), u2h(v5.y)), __hadd2(u2h(v6.y), u2h(v7.y))));
            float2 fx = __half22float2(sx), fy = __half22float2(sy);
            a.x += fx.x; a.y += fx.y; a.z += fy.x; a.w += fy.y;
        } else if (rem >= 4) {
            int4 q = *reinterpret_cast<const int4*>(&rowlist[beg + i]);
            uint2 v0 = y[(size_t)q.x * 32 + sl];
            uint2 v1 = y[(size_t)q.y * 32 + sl];
            uint2 v2 = y[(size_t)q.z * 32 + sl];
            uint2 v3 = y[(size_t)q.w * 32 + sl];
            __half2 sx = __hadd2(__hadd2(u2h(v0.x), u2h(v1.x)), __hadd2(u2h(v2.x), u2h(v3.x)));
            __half2 sy = __hadd2(__hadd2(u2h(v0.y), u2h(v1.y)), __hadd2(u2h(v2.y), u2h(v3.y)));
            float2 fx = __half22float2(sx), fy = __half22float2(sy);
            a.x += fx.x; a.y += fx.y; a.z += fy.x; a.w += fy.y;
            for (unsigned k = 4; k < rem; ++k) acc4(y, rowlist[beg + i + k], sl, a);
        } else if (rem) {
            for (unsigned k = 0; k < rem; ++k) acc4(y, rowlist[beg + i + k], sl, a);
        }
    }
    {
        unsigned rem = deg > i ? deg - i : 0;
        if (rem >= 4) {
            int4 q = *reinterpret_cast<const int4*>(&rowlist[beg + i]);
            uint2 v0 = y[(size_t)q.x * 32 + sl];
            uint2 v1 = y[(size_t)q.y * 32 + sl];
            uint2 v2 = y[(size_t)q.z * 32 + sl];
            uint2 v3 = y[(size_t)q.w * 32 + sl];
            __half2 sx = __hadd2(__hadd2(u2h(v0.x), u2h(v1.x)), __hadd2(u2h(v2.x), u2h(v3.x)));
            __half2 sy = __hadd2(__hadd2(u2h(v0.y), u2h(v1.y)), __hadd2(u2h(v2.y), u2h(v3.y)));
            float2 fx = __half22float2(sx), fy = __half22float2(sy);
            a.x += fx.x; a.y += fx.y; a.z += fy.x; a.w += fy.y;
            for (unsigned k = 4; k < rem; ++k) acc4(y, rowlist[beg + i + k], sl, a);
        } else if (rem) {
            for (unsigned k = 0; k < rem; ++k) acc4(y, rowlist[beg + i + k], sl, a);
        }
    }
    return a;
}

__device__ __forceinline__ uint2 pack4(float a, float b, float c, float d) {
    uint2 r;
    __half2 h0 = __floats2half2_rn(a, b), h1 = __floats2half2_rn(c, d);
    r.x = *reinterpret_cast<unsigned*>(&h0);
    r.y = *reinterpret_cast<unsigned*>(&h1);
    return r;
}

// ---- online-softmax prop path ------------------------------------------

__global__ void __launch_bounds__(256, 8)
prop0_kernel(const uint2* __restrict__ y0,
             const int* __restrict__ rowlist, const unsigned* __restrict__ colptr,
             const float* __restrict__ dinv, const float* __restrict__ rec,
             const float* __restrict__ wkq_ck,
             uint2* __restrict__ yout, uint2* __restrict__ U,
             float* __restrict__ m_run, float* __restrict__ den_run, int n) {
    int wid = threadIdx.x >> 6, lane = threadIdx.x & 63;
    int sub = lane >> 5, sl = lane & 31;
    int c = blockIdx.x * 8 + wid * 2 + sub;
    if (c >= n) c = n - 1;
    unsigned beg = colptr[c], end = colptr[c + 1];
    unsigned deg = end - beg;
    unsigned dego = __shfl_xor(deg, 32, 64);
    unsigned mxd = deg > dego ? deg : dego;
    float4 a = gatherw(y0, rowlist, beg, deg, mxd, sl);

    float dc = dinv[c], rc = rec[c];
    size_t off = (size_t)c * 32 + sl;
    uint2 bvv = y0[off];
    float2 b0 = __half22float2(u2h(bvv.x));
    float2 b1 = __half22float2(u2h(bvv.y));
    float x0 = rc * b0.x, x1 = rc * b0.y, x2 = rc * b1.x, x3 = rc * b1.y;
    float p0 = dc * a.x, p1 = dc * a.y, p2 = dc * a.z, p3 = dc * a.w;
    float ad0 = x0 + p0, ad1 = x1 + p1, ad2 = x2 + p2, ad3 = x3 + p3;
    float sb0 = x0 - p0, sb1 = x1 - p1, sb2 = x2 - p2, sb3 = x3 - p3;
    yout[off] = pack4(dc * sb0, dc * sb1, dc * sb2, dc * sb3);

    const float scale = 0.08838834764831845f;  // 1/sqrt(128)
    float ck = wkq_ck[DFEAT];
    float4 wv = *reinterpret_cast<const float4*>(&wkq_ck[sl * 4]);
    float s0 = (hred(ad0 * wv.x + ad1 * wv.y + ad2 * wv.z + ad3 * wv.w) + ck) * scale;
    float s1 = (hred(sb0 * wv.x + sb1 * wv.y + sb2 * wv.z + sb3 * wv.w) + ck) * scale;
    float m = fmaxf(s0, s1);
    float e0 = expf(s0 - m), e1 = expf(s1 - m);
    U[off] = pack4(e0 * ad0 + e1 * sb0, e0 * ad1 + e1 * sb1,
                   e0 * ad2 + e1 * sb2, e0 * ad3 + e1 * sb3);
    if (sl == 0) { m_run[c] = m; den_run[c] = e0 + e1; }
}

__global__ void __launch_bounds__(256, 8)
prop_fused_kernel(const uint2* __restrict__ y, const int* __restrict__ rowlist,
                  const unsigned* __restrict__ colptr,
                  const float* __restrict__ dinv2, const float* __restrict__ rec,
                  const float* __restrict__ wkq_ck,
                  uint2* __restrict__ yout, uint2* __restrict__ U,
                  float* __restrict__ m_run, float* __restrict__ den_run, int n) {
    int wid = threadIdx.x >> 6, lane = threadIdx.x & 63;
    int sub = lane >> 5, sl = lane & 31;
    int c = blockIdx.x * 8 + wid * 2 + sub;
    if (c >= n) c = n - 1;
    unsigned beg = colptr[c], end = colptr[c + 1];
    unsigned deg = end - beg;
    unsigned dego = __shfl_xor(deg, 32, 64);
    unsigned mxd = deg > dego ? deg : dego;
    float4 a = gatherw(y, rowlist, beg, deg, mxd, sl);

    float d2 = dinv2[c], rc = rec[c];
    size_t off = (size_t)c * 32 + sl;
    uint2 bvv = y[off];
    float2 b0 = __half22float2(u2h(bvv.x));
    float2 b1 = __half22float2(u2h(bvv.y));
    float y0 = b0.x - d2 * a.x, y1 = b0.y - d2 * a.y;
    float y2 = b1.x - d2 * a.z, y3 = b1.y - d2 * a.w;
    yout[off] = pack4(y0, y1, y2, y3);
    float x0 = rc * y0, x1 = rc * y1, x2 = rc * y2, x3 = rc * y3;

    const float scale = 0.08838834764831845f;
    float ck = wkq_ck[DFEAT];
    float4 wv = *reinterpret_cast<const float4*>(&wkq_ck[sl * 4]);
    float s = (hred(x0 * wv.x + x1 * wv.y + x2 * wv.z + x3 * wv.w) + ck) * scale;
    float m = m_run[c], den = den_run[c];
    float m2 = fmaxf(m, s);
    float alpha = expf(m - m2), beta = expf(s - m2);
    uint2 uv = U[off];
    float2 u0 = __half22float2(u2h(uv.x));
    float2 u1 = __half22float2(u2h(uv.y));
    U[off] = pack4(u0.x * alpha + beta * x0, u0.y * alpha + beta * x1,
                   u1.x * alpha + beta * x2, u1.y * alpha + beta * x3);
    if (sl == 0) { m_run[c] = m2; den_run[c] = den * alpha + beta; }
}

// ---- final: out = (U @ Wv)/den + bv via MFMA ---------------------------

__global__ void __launch_bounds__(256, 4)
final_mfma_kernel(const _Float16* __restrict__ Uh, const float* __restrict__ den,
                  const unsigned* __restrict__ wvtU, const float* __restrict__ bv,
                  float* __restrict__ out, int n) {
    __shared__ unsigned wT[8192];
    for (int i = threadIdx.x; i < 8192; i += 256) {
        int col = i >> 6, inner = i & 63;
        wT[col * 64 + (inner ^ ((col & 7) << 2))] = wvtU[i];
    }
    __syncthreads();
    int wave = threadIdx.x >> 6, lane = threadIdx.x & 63;
    int row0 = blockIdx.x * 64 + wave * 16;
    int l15 = lane & 15, grp = lane >> 4;
    int kgrp = grp * 8;
    int arow = row0 + l15; if (arow >= n) arow = n - 1;
    const _Float16* aptr = Uh + (size_t)arow * DFEAT + kgrp;
    half8 af[4];
    af[0] = *(const half8*)(aptr);
    af[1] = *(const half8*)(aptr + 32);
    af[2] = *(const half8*)(aptr + 64);
    af[3] = *(const half8*)(aptr + 96);
    const _Float16* wTh = (const _Float16*)wT;
    floatx4 acc[8];
#pragma unroll
    for (int ct = 0; ct < 8; ++ct) acc[ct] = (floatx4){0.f, 0.f, 0.f, 0.f};
#pragma unroll
    for (int kt = 0; kt < 4; ++kt) {
        int kbase = kt * 32 + kgrp;
#pragma unroll
        for (int ct = 0; ct < 8; ++ct) {
            int col = ct * 16 + l15;
            half8 bf = *(const half8*)&wTh[col * 128 + (kbase ^ ((col & 7) << 3))];
            acc[ct] = __builtin_amdgcn_mfma_f32_16x16x32_f16(af[kt], bf, acc[ct], 0, 0, 0);
        }
    }
    int m0 = row0 + grp * 4;
    float invd[4];
#pragma unroll
    for (int r = 0; r < 4; ++r) {
        int gr = m0 + r;
        invd[r] = 1.0f / den[gr < n ? gr : (n - 1)];
    }
#pragma unroll
    for (int ct = 0; ct < 8; ++ct) {
        int col = ct * 16 + l15;
        float bvc = bv[col];
#pragma unroll
        for (int r = 0; r < 4; ++r) {
            int gr = m0 + r;
            if (gr < n) out[(size_t)gr * DFEAT + col] = acc[ct][r] * invd[r] + bvc;
        }
    }
}

// ------------------------------------------------------------------------

extern "C" void kernel_launch(void* const* d_in, const int* in_sizes, int n_in,
                              void* d_out, int out_size, void* d_ws, size_t ws_size,
                              hipStream_t stream) {
    const float* h_train = (const float*)d_in[0];
    const float* h_ori   = (const float*)d_in[1];
    const int*   eidx    = (const int*)d_in[2];
    const float* Wq = (const float*)d_in[3];
    const float* bq = (const float*)d_in[4];
    const float* Wk = (const float*)d_in[5];
    const float* bk = (const float*)d_in[6];
    const float* Wv = (const float*)d_in[7];
    const float* bv = (const float*)d_in[8];
    float* out = (float*)d_out;

    const int n = in_sizes[0] / DFEAT;   // 100000
    const int E = in_sizes[2] / 2;       // 1600000
    const int NBUK = (n + 255) >> 8;     // 391
    const int EB = (E + 8191) / 8192;    // 196
    size_t FB = align256((size_t)n * 256);   // bytes per fp16 feature buffer

    if (NBUK > 512) return;

    char* p = (char*)d_ws;
    auto alloc = [&](size_t bytes) { char* r = p; p += align256(bytes); return r; };
    uint2*    yA       = (uint2*)   alloc(FB);
    uint2*    yB       = (uint2*)   alloc(FB);
    uint2*    U16      = (uint2*)   alloc(FB);
    int*      rowlist  = (int*)     alloc((size_t)(E + 16) * 4);
    unsigned* pairs    = (unsigned*)alloc((size_t)E * 4);
    float*    dinv     = (float*)   alloc((size_t)n * 4);
    float*    dinv2    = (float*)   alloc((size_t)n * 4);
    float*    rec      = (float*)   alloc((size_t)n * 4);
    unsigned* cnt_row  = (unsigned*)alloc((size_t)n * 4);
    unsigned* colptr   = (unsigned*)alloc((size_t)(n + 1) * 4);
    unsigned* bcount   = (unsigned*)alloc((size_t)NBUK * 4);
    unsigned* bbase    = (unsigned*)alloc((size_t)(NBUK + 1) * 4);
    unsigned* bcur     = (unsigned*)alloc((size_t)NBUK * 4);
    float*    m_run    = (float*)   alloc((size_t)n * 4);
    float*    den_run  = (float*)   alloc((size_t)n * 4);
    float*    partialT = (float*)   alloc((size_t)NPART * DFEAT * 4);
    float*    hbar     = (float*)   alloc(DFEAT * 4);
    float*    wkq_ck   = (float*)   alloc((DFEAT + 1) * 4);
    _Float16* wvt      = (_Float16*)alloc((size_t)DFEAT * DFEAT * 2);
    if ((size_t)(p - (char*)d_ws) > ws_size) return;  // fail loud, not a crash

    hipMemsetAsync(cnt_row, 0, (size_t)n * 4, stream);
    hipMemsetAsync(bcount, 0, (size_t)NBUK * 4, stream);

    hist_kernel<<<EB, 1024, 0, stream>>>(eidx, cnt_row, bcount, E, NBUK);
    bscan_kernel<<<1, 512, 0, stream>>>(bcount, bbase, bcur, colptr, NBUK, n, E);
    dinv_kernel<<<(n + 255) / 256, 256, 0, stream>>>(cnt_row, dinv, dinv2, rec, n);
    bscatter_kernel<<<EB, 1024, 0, stream>>>(eidx, bcur, pairs, E);
    bsort_kernel<<<NBUK, 1024, 0, stream>>>(pairs, bbase, colptr, rowlist, n);

    scale_cvt_kernel<<<(n * 64 + 255) / 256, 256, 0, stream>>>(h_train, dinv, (__half2*)yA, n * 64);
    cvt_wvt_kernel<<<64, 256, 0, stream>>>(Wv, wvt);
    colmean_partial_kernel<<<NPART, 256, 0, stream>>>(h_ori, partialT, n);
    hbar_reduce_kernel<<<DFEAT, 256, 0, stream>>>(partialT, hbar, 1.0f / (float)n);
    wkq_kernel<<<1, 256, 0, stream>>>(hbar, Wq, bq, Wk, bk, wkq_ck);

    int pgrid = (n + 7) / 8;
    prop0_kernel<<<pgrid, 256, 0, stream>>>(yA, rowlist, colptr, dinv, rec, wkq_ck,
                                            yB, U16, m_run, den_run, n);
    uint2* xin = yB; uint2* xout = yA;
    for (int t = 2; t <= 7; ++t) {
        prop_fused_kernel<<<pgrid, 256, 0, stream>>>(xin, rowlist, colptr, dinv2, rec, wkq_ck,
                                                     xout, U16, m_run, den_run, n);
        uint2* tmp = xin; xin = xout; xout = tmp;
    }
    final_mfma_kernel<<<(n + 63) / 64, 256, 0, stream>>>((const _Float16*)U16, den_run,
                                                         (const unsigned*)wvt, bv, out, n);
}